// Round 18
// baseline (629.009 us; speedup 1.0000x reference)
//
#include <hip/hip_runtime.h>
#include <cstdint>

#define DEV __device__ __forceinline__

static constexpr float INV_SQRT_W = 0.04419417382415922f; // 1/sqrt(512)

typedef _Float16 half8 __attribute__((ext_vector_type(8)));
typedef _Float16 half2v __attribute__((ext_vector_type(2)));
typedef float    f32x4 __attribute__((ext_vector_type(4)));

#define GLL16(g, l) __builtin_amdgcn_global_load_lds( \
    (const __attribute__((address_space(1))) void*)(g), \
    (__attribute__((address_space(3))) void*)(l), 16, 0, 0)

DEV int imax(int a, int b) { return a > b ? a : b; }
DEV int imin(int a, int b) { return a < b ? a : b; }

// styles[n][c] = w[n]·aw[c] / sqrt(512) + ab[c]
__global__ __launch_bounds__(256) void k_styles(const float* __restrict__ w,
    const float* __restrict__ aw, const float* __restrict__ ab,
    float* __restrict__ styles) {
  int t = blockIdx.x * 256 + threadIdx.x;        // 4096
  int n = t >> 9, c = t & 511;
  const float* wr = w + n * 512;
  const float* ar = aw + c * 512;
  float s = 0.f;
  for (int k = 0; k < 512; ++k) s = fmaf(wr[k], ar[k], s);
  styles[t] = s * INV_SQRT_W + ab[c];
}

// wsq[o][i] = sum_k w[o,i,k]^2 ; wscale[o] = rsqrt(mean over 4608)
__global__ __launch_bounds__(256) void k_wstats(const float* __restrict__ cw,
    float* __restrict__ wsq, float* __restrict__ wscale) {
  int o = blockIdx.x;
  __shared__ float red[256];
  float tot = 0.f;
  for (int i = threadIdx.x; i < 512; i += 256) {
    const float* p = cw + (o * 512 + i) * 9;
    float s = 0.f;
#pragma unroll
    for (int k = 0; k < 9; ++k) s = fmaf(p[k], p[k], s);
    wsq[o * 512 + i] = s;
    tot += s;
  }
  red[threadIdx.x] = tot;
  __syncthreads();
  for (int st = 128; st > 0; st >>= 1) {
    if (threadIdx.x < st) red[threadIdx.x] += red[threadIdx.x + st];
    __syncthreads();
  }
  if (threadIdx.x == 0) wscale[o] = rsqrtf(red[0] / 4608.f);
}

// sg = rsqrt(mean(styles^2)) over all 4096
__global__ __launch_bounds__(256) void k_sg(const float* __restrict__ styles,
                                            float* __restrict__ sg) {
  __shared__ float red[256];
  float s = 0.f;
  for (int t = threadIdx.x; t < 4096; t += 256) { float v = styles[t]; s = fmaf(v, v, s); }
  red[threadIdx.x] = s;
  __syncthreads();
  for (int st = 128; st > 0; st >>= 1) {
    if (threadIdx.x < st) red[threadIdx.x] += red[threadIdx.x + st];
    __syncthreads();
  }
  if (threadIdx.x == 0) sg[0] = rsqrtf(red[0] / 4096.f);
}

// coef[n][o] = ig * rsqrt(a^2*Q + 1e-8), a = wscale[o]*sg
__global__ __launch_bounds__(256) void k_coef(const float* __restrict__ styles,
    const float* __restrict__ wsq, const float* __restrict__ wscale,
    const float* __restrict__ sg, const float* __restrict__ ema,
    float* __restrict__ coef) {
  int n = blockIdx.x >> 1;
  int o = ((blockIdx.x & 1) << 8) + threadIdx.x;
  __shared__ float s2[512];
  for (int i = threadIdx.x; i < 512; i += 256) { float v = styles[n * 512 + i]; s2[i] = v * v; }
  __syncthreads();
  const float* wq = wsq + o * 512;
  float Q = 0.f;
  for (int i = 0; i < 512; ++i) Q = fmaf(s2[i], wq[i], Q);
  float a = wscale[o] * sg[0];
  float ig = rsqrtf(ema[0]);
  coef[n * 512 + o] = ig * rsqrtf(a * a * Q + 1e-8f);
}

// xT[n][ic][r][c][slot s][j] = f16( x[n, ic*32 + (s^sig(r,c))*8+j, r, c] * styles * sg )
// LDS-transposed; sig = ((r*68+c+2)>>1)&3.
__global__ __launch_bounds__(256) void k_xprep(const float* __restrict__ x,
    const float* __restrict__ styles, const float* __restrict__ sg,
    _Float16* __restrict__ xT) {
  const int b = blockIdx.x;                 // 8*16*64 = 8192
  const int r = b & 63, ic = (b >> 6) & 15, n = b >> 10;
  const int tid = threadIdx.x;
  __shared__ _Float16 ls[32][64];           // 4 KB
  __shared__ float sty[32];
  if (tid < 32) sty[tid] = styles[n * 512 + ic * 32 + tid] * sg[0];
  __syncthreads();
  const float* xb = x + (((size_t)n * 512 + ic * 32) * 64 + r) * 64;
#pragma unroll
  for (int it = 0; it < 8; ++it) {
    int i = it * 4 + (tid >> 6);
    int c = tid & 63;
    float v = xb[(size_t)i * 4096 + c];     // lanes along c: 256B coalesced
    ls[i][c] = (_Float16)(v * sty[i]);
  }
  __syncthreads();
  const int c = tid >> 2, s = tid & 3;
  const int sig = ((r * 68 + c + 2) >> 1) & 3;
  const int ib = (s ^ sig) * 8;
  half8 v;
#pragma unroll
  for (int j = 0; j < 8; ++j) v[j] = ls[ib + j][c];
  *(half8*)(xT + ((((size_t)(n * 16 + ic) * 64 + r) * 64 + c) * 32) + s * 8) = v;
}

// w2[k9][ic][o][iw] = f16( cw[o, ic*32+iw, k9] * wscale[o] )
__global__ __launch_bounds__(256) void k_wprep(const float* __restrict__ cw,
    const float* __restrict__ wscale, _Float16* __restrict__ w2) {
  int t = blockIdx.x * 256 + threadIdx.x;    // 294912 slots of 8 halfs
  int s = t & 3;
  int o = (t >> 2) & 511;
  int ic = (t >> 11) & 15;
  int k9 = t >> 15;                          // 0..8
  float wsc = wscale[o];
  half8 v;
#pragma unroll
  for (int j = 0; j < 8; ++j) {
    int i = ic * 32 + s * 8 + j;
    v[j] = (_Float16)(cw[((size_t)o * 512 + i) * 9 + k9] * wsc);
  }
  *(half8*)(w2 + (size_t)t * 8) = v;
}

// Implicit-GEMM conv via MFMA f16 — K-split x2 + dbuf staging (R16 frame), waves
// now split along o ONLY: wave = 32o x 128p. Removes wp-duplication of A-fragment
// reads (chip A L2-traffic 2.58 -> 1.29 GB); B ds_reads 4->8 per wave (LDS cheap).
__global__ __launch_bounds__(256, 3) void k_conv(
    const _Float16* __restrict__ xT, const _Float16* __restrict__ w2,
    const float* __restrict__ coef, _Float16* __restrict__ convpart) {
  const int b = blockIdx.x;
  const int kx = b & 7;
  const int j = b >> 3;
  const int ot = kx >> 1;
  const int n = (kx & 1) * 4 + j / 70;
  const int jj0 = j % 70;
  const int pt = jj0 >> 1;
  const int kh = jj0 & 1;
  const int p0 = pt * 128;
  const int R0 = p0 / 66;
  const int oBase = ot * 128;

  const int tid = threadIdx.x;
  const int wo4 = tid >> 6;           // wave id: o-quarter (32 o each)
  const int lane = tid & 63;
  const int isub = lane >> 4;
  const int l15 = lane & 15;

  __shared__ _Float16 patch[2][10880];   // [5][68][32] halfs each, 21760 B per buf

  int rloc[8], rr2[8], cc[8]; bool valid[8];
#pragma unroll
  for (int nt = 0; nt < 8; ++nt) {
    int p = p0 + nt * 16 + l15;
    valid[nt] = (p < 4356);
    if (!valid[nt]) p = 4355;
    int r = p / 66;
    rloc[nt] = r - R0;            // 0..2
    rr2[nt] = r - 2;              // input-row base (dr=0)
    cc[nt] = p - r * 66;
  }

  f32x4 acc[2][8];
#pragma unroll
  for (int mt = 0; mt < 2; ++mt)
#pragma unroll
    for (int nt = 0; nt < 8; ++nt) acc[mt][nt] = (f32x4){0.f, 0.f, 0.f, 0.f};

  const int oA = oBase + wo4 * 32 + l15;
  const _Float16* wp0 = w2 + (size_t)oA * 32 + isub * 8;

  // ---- hoisted halo zeroing: identical for every ic; both buffers ----
#pragma unroll
  for (int buf = 0; buf < 2; ++buf) {
    _Float16* dst = &patch[buf][0];
    if (tid < 80) {
      int pix = tid >> 2, s = tid & 3;
      int rl = pix >> 2, ci = pix & 3;
      int cl = (ci < 2) ? ci : (ci + 64);
      half8 z = {};
      *(half8*)(dst + (rl * 68 + cl) * 32 + s * 8) = z;
    }
#pragma unroll
    for (int rl = 0; rl < 5; ++rl) {
      int rin = R0 - 2 + rl;
      if (rin < 0 || rin >= 64) {
        for (int u = tid; u < 272; u += 256) {
          half8 z = {};
          *(half8*)(dst + rl * 68 * 32 + u * 8) = z;
        }
      }
    }
  }

  auto stage_rows = [&](int ic, int buf) {
    const _Float16* src = xT + ((size_t)(n * 16 + ic) * 4096) * 32;
    _Float16* dst = &patch[buf][0];
#pragma unroll
    for (int rl = 0; rl < 5; ++rl) {
      int rin = R0 - 2 + rl;
      if (rin >= 0 && rin < 64)
        GLL16(src + (size_t)rin * 2048 + tid * 8, dst + (rl * 68 + 2) * 32 + tid * 8);
    }
  };

  const int ic0 = kh * 8;
  stage_rows(ic0, 0);
  __syncthreads();

  for (int icl = 0; icl < 8; ++icl) {
    const int ic = ic0 + icl;
    const int buf = icl & 1;
    const _Float16* pb = &patch[buf][0];
    if (icl < 7) stage_rows(ic + 1, buf ^ 1);

#pragma unroll
    for (int k9 = 0; k9 < 9; ++k9) {
      const int dr = k9 / 3, dc = k9 % 3;
      half8 aF[2];
#pragma unroll
      for (int mt = 0; mt < 2; ++mt)
        aF[mt] = *(const half8*)(wp0 + ((size_t)(k9 * 16 + ic) * 512 + mt * 16) * 32);
#pragma unroll
      for (int nt = 0; nt < 8; ++nt) {
        int rl = rloc[nt] + dr;
        int cl = cc[nt] + dc;
        int sig = (((rr2[nt] + dr) * 68 + cl) >> 1) & 3;
        int ah = (rl * 68 + cl) * 32 + ((isub ^ sig) << 3);
        half8 bF = *(const half8*)(pb + ah);
#pragma unroll
        for (int mt = 0; mt < 2; ++mt)
          acc[mt][nt] = __builtin_amdgcn_mfma_f32_16x16x32_f16(aF[mt], bF, acc[mt][nt], 0, 0, 0);
      }
    }
    __syncthreads();
  }

  // epilogue: C layout col=l15 (p), row=isub*4+j (o); scale by coef; f16 partial
  _Float16* outbase = convpart + (size_t)kh * 17842176;
#pragma unroll
  for (int mt = 0; mt < 2; ++mt) {
    const int o = oBase + wo4 * 32 + mt * 16 + isub * 4;
#pragma unroll
    for (int jj = 0; jj < 4; ++jj) {
      const float cf = coef[n * 512 + o + jj];
      _Float16* outp = outbase + (size_t)(n * 512 + o + jj) * 4356;
#pragma unroll
      for (int nt = 0; nt < 8; ++nt) {
        if (valid[nt]) {
          int p = p0 + nt * 16 + l15;
          outp[p] = (_Float16)(acc[mt][nt][jj] * cf);
        }
      }
    }
  }
}

// Fused bias + up-FIR(x2, polyphase) + lrelu + clamp + down-FIR(/2).
// LDS-vectorized; stage3b now computes 2 outputs per thread sharing f32x4 U
// reads (12 -> 4 reads per pair; per-output fma order unchanged).
__global__ __launch_bounds__(256) void k_flrelu(const _Float16* __restrict__ convpart,
    const float* __restrict__ cbias, const float* __restrict__ fu,
    const float* __restrict__ fd, float* __restrict__ out) {
  const int img = blockIdx.x >> 2;       // n*512+c
  const int tile = blockIdx.x & 3;
  const int P0 = tile * 16;              // output rows [P0, P0+16)
  const int c = img & 511;
  const int tid = threadIdx.x;

  __shared__ alignas(16) float As[26 * 68];  // conv rows (+bias); aliased as U chunk
  __shared__ alignas(16) float Bs[42 * 80];  // v-up rows, col offset +4, zero aprons
  __shared__ alignas(16) float Vs[42 * 64];  // after horizontal up+lrelu+down

  float fupr[12], fdr[12];
#pragma unroll
  for (int jj = 0; jj < 12; ++jj) { fupr[jj] = fu[jj]; fdr[jj] = fd[11 - jj]; }

  // stage 1: A rows [P0-4, P0+21] = partA + partB + bias; f16-pair loads
  {
    const _Float16* srcA = convpart + (size_t)img * 4356;
    const _Float16* srcB = srcA + 17842176;
    const float bias = cbias[c];
    for (int t = tid; t < 26 * 34; t += 256) {
      int r = t / 34, cp = t - r * 34;       // pair of cols (2cp, 2cp+1)
      int gr = P0 - 4 + r;
      float2 v = make_float2(0.f, 0.f);
      if (cp < 33 && gr >= 0 && gr < 66) {
        int idx = gr * 66 + 2 * cp;
        half2v a = *(const half2v*)(srcA + idx);
        half2v b2 = *(const half2v*)(srcB + idx);
        v.x = (float)a[0] + (float)b2[0] + bias;
        v.y = (float)a[1] + (float)b2[1] + bias;
      }
      *(float2*)&As[r * 68 + 2 * cp] = v;
    }
  }
  __syncthreads();

  // stage 2: vertical up-FIR, 4 cols/thread via float4 (cols m = 4g..4g+3, g<17)
  for (int t = tid; t < 42 * 17; t += 256) {
    int k = t / 17, g = t - k * 17;
    int e = k & 1, kk = (k - e) >> 1;
    const float* Ab = &As[kk * 68 + 4 * g];
    float s0 = 0.f, s1 = 0.f, s2 = 0.f, s3 = 0.f;
#pragma unroll
    for (int jj = 0; jj < 6; ++jj) {
      f32x4 a = *(const f32x4*)(Ab + (5 - jj) * 68);
      float f = e ? fupr[2 * jj + 1] : fupr[2 * jj];
      s0 = fmaf(f, a[0], s0);
      s1 = fmaf(f, a[1], s1);
      s2 = fmaf(f, a[2], s2);
      s3 = fmaf(f, a[3], s3);
    }
    f32x4 sv = {s0, s1, s2, s3};
    *(f32x4*)&Bs[k * 80 + 4 + 4 * g] = sv;    // covers B cols 0..67 (66,67 are 0)
  }
  // aprons: cols [0,4) and [72,80)
  for (int t = tid; t < 42 * 12; t += 256) {
    int k = t / 12, ci = t - k * 12;
    int col = (ci < 4) ? ci : (68 + ci);      // 0..3, 72..79
    Bs[k * 80 + col] = 0.f;
  }
  __syncthreads();        // As dead from here; reuse as U

  // stage 3 (chunked 12 rows; 12*140=1680 <= 1768 floats of As).
  float* Us = As;
  for (int kc = 0; kc < 4; ++kc) {
    const int k0 = kc * 12;
    const int nrows = imin(42 - k0, 12);
    // 3a: one 9-float window -> 8 U values
    for (int t = tid; t < nrows * 18; t += 256) {
      int kr = t / 18, g = t - kr * 18;
      const float* Bk = &Bs[(k0 + kr) * 80 + 4 * g];
      float b[9];
#pragma unroll
      for (int u = 0; u < 9; ++u) b[u] = Bk[u];
      float u8[8];
#pragma unroll
      for (int u = 0; u < 4; ++u) {
        float ue = 0.f, uo = 0.f;
#pragma unroll
        for (int jj = 0; jj < 6; ++jj) {
          float bb = b[u + 5 - jj];
          ue = fmaf(fupr[2 * jj], bb, ue);
          uo = fmaf(fupr[2 * jj + 1], bb, uo);
        }
        ue *= (ue >= 0.f) ? 5.65685424949238f : 1.13137084989848f;
        uo *= (uo >= 0.f) ? 5.65685424949238f : 1.13137084989848f;
        ue = fminf(256.f, fmaxf(-256.f, ue));
        uo = fminf(256.f, fmaxf(-256.f, uo));
        u8[2 * u] = ue; u8[2 * u + 1] = uo;
      }
      float* Ud = &Us[kr * 140 + 8 * g];
      f32x4 lo = {u8[0], u8[1], u8[2], u8[3]};
      *(f32x4*)(Ud) = lo;
      if (4 * g + 2 < 70) {
        f32x4 hi = {u8[4], u8[5], u8[6], u8[7]};
        *(f32x4*)(Ud + 4) = hi;
      }
    }
    __syncthreads();
    // 3b: horizontal down-FIR, 2 outputs/thread sharing 4 f32x4 U reads
    for (int t = tid; t < nrows * 32; t += 256) {
      int kr = t >> 5, qp = t & 31;           // outputs q = 2qp, 2qp+1
      const float* Ur = &Us[kr * 140 + 4 * qp];
      f32x4 a0 = *(const f32x4*)(Ur);
      f32x4 a1 = *(const f32x4*)(Ur + 4);
      f32x4 a2 = *(const f32x4*)(Ur + 8);
      f32x4 a3 = *(const f32x4*)(Ur + 12);
      float u[16] = {a0[0], a0[1], a0[2], a0[3], a1[0], a1[1], a1[2], a1[3],
                     a2[0], a2[1], a2[2], a2[3], a3[0], a3[1], a3[2], a3[3]};
      float v0 = 0.f, v1 = 0.f;
#pragma unroll
      for (int jj = 0; jj < 12; ++jj) {
        v0 = fmaf(fdr[jj], u[jj], v0);
        v1 = fmaf(fdr[jj], u[jj + 2], v1);
      }
      *(float2*)&Vs[(k0 + kr) * 64 + 2 * qp] = make_float2(v0, v1);
    }
    __syncthreads();
  }

  // stage 4: vertical down-FIR, 4 outputs/thread via float4 (16 pr x 16 qg)
  {
    int pr = tid >> 4, qg = tid & 15;
    const float* Vb = &Vs[(2 * pr) * 64 + 4 * qg];
    float s0 = 0.f, s1 = 0.f, s2 = 0.f, s3 = 0.f;
#pragma unroll
    for (int jj = 0; jj < 12; ++jj) {
      f32x4 vv = *(const f32x4*)(Vb + jj * 64);
      float f = fdr[jj];
      s0 = fmaf(f, vv[0], s0);
      s1 = fmaf(f, vv[1], s1);
      s2 = fmaf(f, vv[2], s2);
      s3 = fmaf(f, vv[3], s3);
    }
    f32x4 sv = {s0, s1, s2, s3};
    *(f32x4*)(out + (size_t)img * 4096 + (P0 + pr) * 64 + 4 * qg) = sv;
  }
}

extern "C" void kernel_launch(void* const* d_in, const int* in_sizes, int n_in,
                              void* d_out, int out_size, void* d_ws, size_t ws_size,
                              hipStream_t stream) {
  const float* x   = (const float*)d_in[0];
  const float* w   = (const float*)d_in[1];
  const float* aw  = (const float*)d_in[2];
  const float* ab  = (const float*)d_in[3];
  const float* cw  = (const float*)d_in[4];
  const float* cb  = (const float*)d_in[5];
  const float* fu  = (const float*)d_in[6];
  const float* fd  = (const float*)d_in[7];
  const float* ema = (const float*)d_in[8];
  float* out = (float*)d_out;

  float* ws       = (float*)d_ws;
  float* styles   = ws;                         // 4096
  float* wsq      = styles + 4096;              // 262144
  float* wscale   = wsq + 262144;               // 512
  float* coef     = wscale + 512;               // 4096
  float* sg       = coef + 4096;                // 8
  _Float16* convpart = (_Float16*)(sg + 8);     // 2 x 17,842,176 halfs (71.4 MB)
  _Float16* xT    = convpart + 35684352;        // 16,777,216 halfs
  _Float16* w2    = xT + 16777216;              // 2,359,296 halfs
  // total = 110,725,152 B == proven footprint

  k_styles<<<16, 256, 0, stream>>>(w, aw, ab, styles);
  k_sg<<<1, 256, 0, stream>>>(styles, sg);
  k_wstats<<<512, 256, 0, stream>>>(cw, wsq, wscale);
  k_coef<<<16, 256, 0, stream>>>(styles, wsq, wscale, sg, ema, coef);
  k_xprep<<<8192, 256, 0, stream>>>(x, styles, sg, xT);
  k_wprep<<<1152, 256, 0, stream>>>(cw, wscale, w2);
  k_conv<<<2240, 256, 0, stream>>>(xT, w2, coef, convpart);
  k_flrelu<<<16384, 256, 0, stream>>>(convpart, cb, fu, fd, out);
}

// Round 19
// 371.033 us; speedup vs baseline: 1.6953x; 1.6953x over previous
//
#include <hip/hip_runtime.h>
#include <cstdint>

#define DEV __device__ __forceinline__

static constexpr float INV_SQRT_W = 0.04419417382415922f; // 1/sqrt(512)

typedef _Float16 half8 __attribute__((ext_vector_type(8)));
typedef _Float16 half2v __attribute__((ext_vector_type(2)));
typedef float    f32x4 __attribute__((ext_vector_type(4)));

#define GLL16(g, l) __builtin_amdgcn_global_load_lds( \
    (const __attribute__((address_space(1))) void*)(g), \
    (__attribute__((address_space(3))) void*)(l), 16, 0, 0)

DEV int imax(int a, int b) { return a > b ? a : b; }
DEV int imin(int a, int b) { return a < b ? a : b; }

// styles[n][c] = w[n]·aw[c] / sqrt(512) + ab[c]   (float4 inner loop)
__global__ __launch_bounds__(256) void k_styles(const float* __restrict__ w,
    const float* __restrict__ aw, const float* __restrict__ ab,
    float* __restrict__ styles) {
  int t = blockIdx.x * 256 + threadIdx.x;        // 4096
  int n = t >> 9, c = t & 511;
  const f32x4* wr = (const f32x4*)(w + n * 512);
  const f32x4* ar = (const f32x4*)(aw + c * 512);
  float s = 0.f;
  for (int k = 0; k < 128; ++k) {
    f32x4 a = wr[k], b = ar[k];
    s = fmaf(a[0], b[0], s);
    s = fmaf(a[1], b[1], s);
    s = fmaf(a[2], b[2], s);
    s = fmaf(a[3], b[3], s);
  }
  styles[t] = s * INV_SQRT_W + ab[c];
}

// wsq[o][i] = sum_k w[o,i,k]^2 ; wscale[o] = rsqrt(mean over 4608)
__global__ __launch_bounds__(256) void k_wstats(const float* __restrict__ cw,
    float* __restrict__ wsq, float* __restrict__ wscale) {
  int o = blockIdx.x;
  __shared__ float red[256];
  float tot = 0.f;
  for (int i = threadIdx.x; i < 512; i += 256) {
    const float* p = cw + (o * 512 + i) * 9;
    float s = 0.f;
#pragma unroll
    for (int k = 0; k < 9; ++k) s = fmaf(p[k], p[k], s);
    wsq[o * 512 + i] = s;
    tot += s;
  }
  red[threadIdx.x] = tot;
  __syncthreads();
  for (int st = 128; st > 0; st >>= 1) {
    if (threadIdx.x < st) red[threadIdx.x] += red[threadIdx.x + st];
    __syncthreads();
  }
  if (threadIdx.x == 0) wscale[o] = rsqrtf(red[0] / 4608.f);
}

// sg = rsqrt(mean(styles^2)) over all 4096
__global__ __launch_bounds__(256) void k_sg(const float* __restrict__ styles,
                                            float* __restrict__ sg) {
  __shared__ float red[256];
  float s = 0.f;
  for (int t = threadIdx.x; t < 4096; t += 256) { float v = styles[t]; s = fmaf(v, v, s); }
  red[threadIdx.x] = s;
  __syncthreads();
  for (int st = 128; st > 0; st >>= 1) {
    if (threadIdx.x < st) red[threadIdx.x] += red[threadIdx.x + st];
    __syncthreads();
  }
  if (threadIdx.x == 0) sg[0] = rsqrtf(red[0] / 4096.f);
}

// coef[n][o] = ig * rsqrt(a^2*Q + 1e-8), a = wscale[o]*sg   (float4 inner loop)
__global__ __launch_bounds__(256) void k_coef(const float* __restrict__ styles,
    const float* __restrict__ wsq, const float* __restrict__ wscale,
    const float* __restrict__ sg, const float* __restrict__ ema,
    float* __restrict__ coef) {
  int n = blockIdx.x >> 1;
  int o = ((blockIdx.x & 1) << 8) + threadIdx.x;
  __shared__ alignas(16) float s2[512];
  for (int i = threadIdx.x; i < 512; i += 256) { float v = styles[n * 512 + i]; s2[i] = v * v; }
  __syncthreads();
  const f32x4* wq = (const f32x4*)(wsq + o * 512);
  const f32x4* sq = (const f32x4*)s2;
  float Q = 0.f;
  for (int i = 0; i < 128; ++i) {
    f32x4 a = sq[i], b = wq[i];
    Q = fmaf(a[0], b[0], Q);
    Q = fmaf(a[1], b[1], Q);
    Q = fmaf(a[2], b[2], Q);
    Q = fmaf(a[3], b[3], Q);
  }
  float a = wscale[o] * sg[0];
  float ig = rsqrtf(ema[0]);
  coef[n * 512 + o] = ig * rsqrtf(a * a * Q + 1e-8f);
}

// xT[n][ic][r][c][slot s][j] = f16( x[n, ic*32 + (s^sig(r,c))*8+j, r, c] * styles * sg )
// LDS-transposed; sig = ((r*68+c+2)>>1)&3.   (R17 verbatim)
__global__ __launch_bounds__(256) void k_xprep(const float* __restrict__ x,
    const float* __restrict__ styles, const float* __restrict__ sg,
    _Float16* __restrict__ xT) {
  const int b = blockIdx.x;                 // 8*16*64 = 8192
  const int r = b & 63, ic = (b >> 6) & 15, n = b >> 10;
  const int tid = threadIdx.x;
  __shared__ _Float16 ls[32][64];           // 4 KB
  __shared__ float sty[32];
  if (tid < 32) sty[tid] = styles[n * 512 + ic * 32 + tid] * sg[0];
  __syncthreads();
  const float* xb = x + (((size_t)n * 512 + ic * 32) * 64 + r) * 64;
#pragma unroll
  for (int it = 0; it < 8; ++it) {
    int i = it * 4 + (tid >> 6);
    int c = tid & 63;
    float v = xb[(size_t)i * 4096 + c];     // lanes along c: 256B coalesced
    ls[i][c] = (_Float16)(v * sty[i]);
  }
  __syncthreads();
  const int c = tid >> 2, s = tid & 3;
  const int sig = ((r * 68 + c + 2) >> 1) & 3;
  const int ib = (s ^ sig) * 8;
  half8 v;
#pragma unroll
  for (int j = 0; j < 8; ++j) v[j] = ls[ib + j][c];
  *(half8*)(xT + ((((size_t)(n * 16 + ic) * 64 + r) * 64 + c) * 32) + s * 8) = v;
}

// w2[k9][ic][o][iw] = f16( cw[o, ic*32+iw, k9] * wscale[o] )   (R17 verbatim)
__global__ __launch_bounds__(256) void k_wprep(const float* __restrict__ cw,
    const float* __restrict__ wscale, _Float16* __restrict__ w2) {
  int t = blockIdx.x * 256 + threadIdx.x;    // 294912 slots of 8 halfs
  int s = t & 3;
  int o = (t >> 2) & 511;
  int ic = (t >> 11) & 15;
  int k9 = t >> 15;                          // 0..8
  float wsc = wscale[o];
  half8 v;
#pragma unroll
  for (int j = 0; j < 8; ++j) {
    int i = ic * 32 + s * 8 + j;
    v[j] = (_Float16)(cw[((size_t)o * 512 + i) * 9 + k9] * wsc);
  }
  *(half8*)(w2 + (size_t)t * 8) = v;
}

// Implicit-GEMM conv via MFMA f16 — R17/R16 verbatim (K-split x2, dbuf staging,
// 2x2 waves of 64o x 64p, acc[4][4]). FROZEN: every wider-wave / reg-ladder /
// sched_barrier variant spilled or regressed (R8/R10/R12/R14/R15/R18).
__global__ __launch_bounds__(256, 3) void k_conv(
    const _Float16* __restrict__ xT, const _Float16* __restrict__ w2,
    const float* __restrict__ coef, _Float16* __restrict__ convpart) {
  const int b = blockIdx.x;
  const int kx = b & 7;
  const int j = b >> 3;
  const int ot = kx >> 1;
  const int n = (kx & 1) * 4 + j / 70;
  const int jj0 = j % 70;
  const int pt = jj0 >> 1;
  const int kh = jj0 & 1;
  const int p0 = pt * 128;
  const int R0 = p0 / 66;
  const int oBase = ot * 128;

  const int tid = threadIdx.x;
  const int wave = tid >> 6;
  const int lane = tid & 63;
  const int wo = wave >> 1, wp = wave & 1;
  const int isub = lane >> 4;
  const int l15 = lane & 15;

  __shared__ _Float16 patch[2][10880];   // [5][68][32] halfs each, 21760 B per buf

  int rloc[4], rr2[4], cc[4]; bool valid[4];
#pragma unroll
  for (int nt = 0; nt < 4; ++nt) {
    int p = p0 + wp * 64 + nt * 16 + l15;
    valid[nt] = (p < 4356);
    if (!valid[nt]) p = 4355;
    int r = p / 66;
    rloc[nt] = r - R0;
    rr2[nt] = r - 2;
    cc[nt] = p - r * 66;
  }

  f32x4 acc[4][4];
#pragma unroll
  for (int mt = 0; mt < 4; ++mt)
#pragma unroll
    for (int nt = 0; nt < 4; ++nt) acc[mt][nt] = (f32x4){0.f, 0.f, 0.f, 0.f};

  const int oA = oBase + wo * 64 + l15;
  const _Float16* wp0 = w2 + (size_t)oA * 32 + isub * 8;

#pragma unroll
  for (int buf = 0; buf < 2; ++buf) {
    _Float16* dst = &patch[buf][0];
    if (tid < 80) {
      int pix = tid >> 2, s = tid & 3;
      int rl = pix >> 2, ci = pix & 3;
      int cl = (ci < 2) ? ci : (ci + 64);
      half8 z = {};
      *(half8*)(dst + (rl * 68 + cl) * 32 + s * 8) = z;
    }
#pragma unroll
    for (int rl = 0; rl < 5; ++rl) {
      int rin = R0 - 2 + rl;
      if (rin < 0 || rin >= 64) {
        for (int u = tid; u < 272; u += 256) {
          half8 z = {};
          *(half8*)(dst + rl * 68 * 32 + u * 8) = z;
        }
      }
    }
  }

  auto stage_rows = [&](int ic, int buf) {
    const _Float16* src = xT + ((size_t)(n * 16 + ic) * 4096) * 32;
    _Float16* dst = &patch[buf][0];
#pragma unroll
    for (int rl = 0; rl < 5; ++rl) {
      int rin = R0 - 2 + rl;
      if (rin >= 0 && rin < 64)
        GLL16(src + (size_t)rin * 2048 + tid * 8, dst + (rl * 68 + 2) * 32 + tid * 8);
    }
  };

  const int ic0 = kh * 8;
  stage_rows(ic0, 0);
  __syncthreads();

  for (int icl = 0; icl < 8; ++icl) {
    const int ic = ic0 + icl;
    const int buf = icl & 1;
    const _Float16* pb = &patch[buf][0];
    if (icl < 7) stage_rows(ic + 1, buf ^ 1);

#pragma unroll
    for (int k9 = 0; k9 < 9; ++k9) {
      const int dr = k9 / 3, dc = k9 % 3;
      half8 aF[4];
#pragma unroll
      for (int mt = 0; mt < 4; ++mt)
        aF[mt] = *(const half8*)(wp0 + ((size_t)(k9 * 16 + ic) * 512 + mt * 16) * 32);
#pragma unroll
      for (int nt = 0; nt < 4; ++nt) {
        int rl = rloc[nt] + dr;
        int cl = cc[nt] + dc;
        int sig = (((rr2[nt] + dr) * 68 + cl) >> 1) & 3;
        int ah = (rl * 68 + cl) * 32 + ((isub ^ sig) << 3);
        half8 bF = *(const half8*)(pb + ah);
#pragma unroll
        for (int mt = 0; mt < 4; ++mt)
          acc[mt][nt] = __builtin_amdgcn_mfma_f32_16x16x32_f16(aF[mt], bF, acc[mt][nt], 0, 0, 0);
      }
    }
    __syncthreads();
  }

  _Float16* outbase = convpart + (size_t)kh * 17842176;
#pragma unroll
  for (int mt = 0; mt < 4; ++mt) {
    const int o = oBase + wo * 64 + mt * 16 + isub * 4;
#pragma unroll
    for (int jj = 0; jj < 4; ++jj) {
      const float cf = coef[n * 512 + o + jj];
      _Float16* outp = outbase + (size_t)(n * 512 + o + jj) * 4356;
#pragma unroll
      for (int nt = 0; nt < 4; ++nt) {
        if (valid[nt]) {
          int p = p0 + wp * 64 + nt * 16 + l15;
          outp[p] = (_Float16)(acc[mt][nt][jj] * cf);
        }
      }
    }
  }
}

// Fused bias + up-FIR(x2, polyphase) + lrelu + clamp + down-FIR(/2).
// R17 verbatim (LDS-vectorized, 16-row tiles, sums 2 f16 partials).
__global__ __launch_bounds__(256) void k_flrelu(const _Float16* __restrict__ convpart,
    const float* __restrict__ cbias, const float* __restrict__ fu,
    const float* __restrict__ fd, float* __restrict__ out) {
  const int img = blockIdx.x >> 2;       // n*512+c
  const int tile = blockIdx.x & 3;
  const int P0 = tile * 16;              // output rows [P0, P0+16)
  const int c = img & 511;
  const int tid = threadIdx.x;

  __shared__ alignas(16) float As[26 * 68];  // conv rows (+bias); aliased as U chunk
  __shared__ alignas(16) float Bs[42 * 80];  // v-up rows, col offset +4, zero aprons
  __shared__ alignas(16) float Vs[42 * 64];  // after horizontal up+lrelu+down

  float fupr[12], fdr[12];
#pragma unroll
  for (int jj = 0; jj < 12; ++jj) { fupr[jj] = fu[jj]; fdr[jj] = fd[11 - jj]; }

  // stage 1: A rows [P0-4, P0+21] = partA + partB + bias; f16-pair loads
  {
    const _Float16* srcA = convpart + (size_t)img * 4356;
    const _Float16* srcB = srcA + 17842176;
    const float bias = cbias[c];
    for (int t = tid; t < 26 * 34; t += 256) {
      int r = t / 34, cp = t - r * 34;       // pair of cols (2cp, 2cp+1)
      int gr = P0 - 4 + r;
      float2 v = make_float2(0.f, 0.f);
      if (cp < 33 && gr >= 0 && gr < 66) {
        int idx = gr * 66 + 2 * cp;
        half2v a = *(const half2v*)(srcA + idx);
        half2v b2 = *(const half2v*)(srcB + idx);
        v.x = (float)a[0] + (float)b2[0] + bias;
        v.y = (float)a[1] + (float)b2[1] + bias;
      }
      *(float2*)&As[r * 68 + 2 * cp] = v;
    }
  }
  __syncthreads();

  // stage 2: vertical up-FIR, 4 cols/thread via float4 (cols m = 4g..4g+3, g<17)
  for (int t = tid; t < 42 * 17; t += 256) {
    int k = t / 17, g = t - k * 17;
    int e = k & 1, kk = (k - e) >> 1;
    const float* Ab = &As[kk * 68 + 4 * g];
    float s0 = 0.f, s1 = 0.f, s2 = 0.f, s3 = 0.f;
#pragma unroll
    for (int jj = 0; jj < 6; ++jj) {
      f32x4 a = *(const f32x4*)(Ab + (5 - jj) * 68);
      float f = e ? fupr[2 * jj + 1] : fupr[2 * jj];
      s0 = fmaf(f, a[0], s0);
      s1 = fmaf(f, a[1], s1);
      s2 = fmaf(f, a[2], s2);
      s3 = fmaf(f, a[3], s3);
    }
    f32x4 sv = {s0, s1, s2, s3};
    *(f32x4*)&Bs[k * 80 + 4 + 4 * g] = sv;    // covers B cols 0..67 (66,67 are 0)
  }
  // aprons: cols [0,4) and [72,80)
  for (int t = tid; t < 42 * 12; t += 256) {
    int k = t / 12, ci = t - k * 12;
    int col = (ci < 4) ? ci : (68 + ci);      // 0..3, 72..79
    Bs[k * 80 + col] = 0.f;
  }
  __syncthreads();        // As dead from here; reuse as U

  // stage 3 (chunked 12 rows; 12*140=1680 <= 1768 floats of As).
  // 3a: one 9-float window -> 8 U values (m = 4g..4g+3).
  float* Us = As;
  for (int kc = 0; kc < 4; ++kc) {
    const int k0 = kc * 12;
    const int nrows = imin(42 - k0, 12);
    for (int t = tid; t < nrows * 18; t += 256) {
      int kr = t / 18, g = t - kr * 18;       // g in [0,18): m base 4g <= 68
      const float* Bk = &Bs[(k0 + kr) * 80 + 4 * g];
      float b[9];
#pragma unroll
      for (int u = 0; u < 9; ++u) b[u] = Bk[u];
      float u8[8];
#pragma unroll
      for (int u = 0; u < 4; ++u) {
        float ue = 0.f, uo = 0.f;
#pragma unroll
        for (int jj = 0; jj < 6; ++jj) {
          float bb = b[u + 5 - jj];
          ue = fmaf(fupr[2 * jj], bb, ue);
          uo = fmaf(fupr[2 * jj + 1], bb, uo);
        }
        ue *= (ue >= 0.f) ? 5.65685424949238f : 1.13137084989848f;
        uo *= (uo >= 0.f) ? 5.65685424949238f : 1.13137084989848f;
        ue = fminf(256.f, fmaxf(-256.f, ue));
        uo = fminf(256.f, fmaxf(-256.f, uo));
        u8[2 * u] = ue; u8[2 * u + 1] = uo;
      }
      float* Ud = &Us[kr * 140 + 8 * g];
      f32x4 lo = {u8[0], u8[1], u8[2], u8[3]};
      *(f32x4*)(Ud) = lo;
      if (4 * g + 2 < 70) {
        f32x4 hi = {u8[4], u8[5], u8[6], u8[7]};
        *(f32x4*)(Ud + 4) = hi;
      }
    }
    __syncthreads();
    // 3b: horizontal down-FIR via 6 float2 reads
    for (int t = tid; t < nrows * 64; t += 256) {
      int kr = t >> 6, q = t & 63;
      const float* Ur = &Us[kr * 140 + 2 * q];
      float v = 0.f;
#pragma unroll
      for (int jj = 0; jj < 6; ++jj) {
        float2 u2 = *(const float2*)(Ur + 2 * jj);
        v = fmaf(fdr[2 * jj], u2.x, v);
        v = fmaf(fdr[2 * jj + 1], u2.y, v);
      }
      Vs[(k0 + kr) * 64 + q] = v;
    }
    __syncthreads();
  }

  // stage 4: vertical down-FIR, 4 outputs/thread via float4 (16 pr x 16 qg)
  {
    int pr = tid >> 4, qg = tid & 15;
    const float* Vb = &Vs[(2 * pr) * 64 + 4 * qg];
    float s0 = 0.f, s1 = 0.f, s2 = 0.f, s3 = 0.f;
#pragma unroll
    for (int jj = 0; jj < 12; ++jj) {
      f32x4 vv = *(const f32x4*)(Vb + jj * 64);
      float f = fdr[jj];
      s0 = fmaf(f, vv[0], s0);
      s1 = fmaf(f, vv[1], s1);
      s2 = fmaf(f, vv[2], s2);
      s3 = fmaf(f, vv[3], s3);
    }
    f32x4 sv = {s0, s1, s2, s3};
    *(f32x4*)(out + (size_t)img * 4096 + (P0 + pr) * 64 + 4 * qg) = sv;
  }
}

extern "C" void kernel_launch(void* const* d_in, const int* in_sizes, int n_in,
                              void* d_out, int out_size, void* d_ws, size_t ws_size,
                              hipStream_t stream) {
  const float* x   = (const float*)d_in[0];
  const float* w   = (const float*)d_in[1];
  const float* aw  = (const float*)d_in[2];
  const float* ab  = (const float*)d_in[3];
  const float* cw  = (const float*)d_in[4];
  const float* cb  = (const float*)d_in[5];
  const float* fu  = (const float*)d_in[6];
  const float* fd  = (const float*)d_in[7];
  const float* ema = (const float*)d_in[8];
  float* out = (float*)d_out;

  float* ws       = (float*)d_ws;
  float* styles   = ws;                         // 4096
  float* wsq      = styles + 4096;              // 262144
  float* wscale   = wsq + 262144;               // 512
  float* coef     = wscale + 512;               // 4096
  float* sg       = coef + 4096;                // 8
  _Float16* convpart = (_Float16*)(sg + 8);     // 2 x 17,842,176 halfs (71.4 MB)
  _Float16* xT    = convpart + 35684352;        // 16,777,216 halfs
  _Float16* w2    = xT + 16777216;              // 2,359,296 halfs
  // total = 110,725,152 B == proven footprint

  k_styles<<<16, 256, 0, stream>>>(w, aw, ab, styles);
  k_sg<<<1, 256, 0, stream>>>(styles, sg);
  k_wstats<<<512, 256, 0, stream>>>(cw, wsq, wscale);
  k_coef<<<16, 256, 0, stream>>>(styles, wsq, wscale, sg, ema, coef);
  k_xprep<<<8192, 256, 0, stream>>>(x, styles, sg, xT);
  k_wprep<<<1152, 256, 0, stream>>>(cw, wscale, w2);
  k_conv<<<2240, 256, 0, stream>>>(xT, w2, coef, convpart);
  k_flrelu<<<16384, 256, 0, stream>>>(convpart, cb, fu, fd, out);
}

// Round 20
// 367.589 us; speedup vs baseline: 1.7112x; 1.0094x over previous
//
#include <hip/hip_runtime.h>
#include <cstdint>

#define DEV __device__ __forceinline__

static constexpr float INV_SQRT_W = 0.04419417382415922f; // 1/sqrt(512)

typedef _Float16 half8 __attribute__((ext_vector_type(8)));
typedef _Float16 half2v __attribute__((ext_vector_type(2)));
typedef float    f32x4 __attribute__((ext_vector_type(4)));

#define GLL16(g, l) __builtin_amdgcn_global_load_lds( \
    (const __attribute__((address_space(1))) void*)(g), \
    (__attribute__((address_space(3))) void*)(l), 16, 0, 0)

DEV int imax(int a, int b) { return a > b ? a : b; }
DEV int imin(int a, int b) { return a < b ? a : b; }

// styles[n][c] = w[n]·aw[c] / sqrt(512) + ab[c]   (float4 inner loop)
__global__ __launch_bounds__(256) void k_styles(const float* __restrict__ w,
    const float* __restrict__ aw, const float* __restrict__ ab,
    float* __restrict__ styles) {
  int t = blockIdx.x * 256 + threadIdx.x;        // 4096
  int n = t >> 9, c = t & 511;
  const f32x4* wr = (const f32x4*)(w + n * 512);
  const f32x4* ar = (const f32x4*)(aw + c * 512);
  float s = 0.f;
  for (int k = 0; k < 128; ++k) {
    f32x4 a = wr[k], b = ar[k];
    s = fmaf(a[0], b[0], s);
    s = fmaf(a[1], b[1], s);
    s = fmaf(a[2], b[2], s);
    s = fmaf(a[3], b[3], s);
  }
  styles[t] = s * INV_SQRT_W + ab[c];
}

// wsq[o][i] = sum_k w[o,i,k]^2 ; wscale[o] = rsqrt(mean over 4608)
__global__ __launch_bounds__(256) void k_wstats(const float* __restrict__ cw,
    float* __restrict__ wsq, float* __restrict__ wscale) {
  int o = blockIdx.x;
  __shared__ float red[256];
  float tot = 0.f;
  for (int i = threadIdx.x; i < 512; i += 256) {
    const float* p = cw + (o * 512 + i) * 9;
    float s = 0.f;
#pragma unroll
    for (int k = 0; k < 9; ++k) s = fmaf(p[k], p[k], s);
    wsq[o * 512 + i] = s;
    tot += s;
  }
  red[threadIdx.x] = tot;
  __syncthreads();
  for (int st = 128; st > 0; st >>= 1) {
    if (threadIdx.x < st) red[threadIdx.x] += red[threadIdx.x + st];
    __syncthreads();
  }
  if (threadIdx.x == 0) wscale[o] = rsqrtf(red[0] / 4608.f);
}

// sg = rsqrt(mean(styles^2)) over all 4096
__global__ __launch_bounds__(256) void k_sg(const float* __restrict__ styles,
                                            float* __restrict__ sg) {
  __shared__ float red[256];
  float s = 0.f;
  for (int t = threadIdx.x; t < 4096; t += 256) { float v = styles[t]; s = fmaf(v, v, s); }
  red[threadIdx.x] = s;
  __syncthreads();
  for (int st = 128; st > 0; st >>= 1) {
    if (threadIdx.x < st) red[threadIdx.x] += red[threadIdx.x + st];
    __syncthreads();
  }
  if (threadIdx.x == 0) sg[0] = rsqrtf(red[0] / 4096.f);
}

// coef[n][o] = ig * rsqrt(a^2*Q + 1e-8), a = wscale[o]*sg   (float4 inner loop)
__global__ __launch_bounds__(256) void k_coef(const float* __restrict__ styles,
    const float* __restrict__ wsq, const float* __restrict__ wscale,
    const float* __restrict__ sg, const float* __restrict__ ema,
    float* __restrict__ coef) {
  int n = blockIdx.x >> 1;
  int o = ((blockIdx.x & 1) << 8) + threadIdx.x;
  __shared__ alignas(16) float s2[512];
  for (int i = threadIdx.x; i < 512; i += 256) { float v = styles[n * 512 + i]; s2[i] = v * v; }
  __syncthreads();
  const f32x4* wq = (const f32x4*)(wsq + o * 512);
  const f32x4* sq = (const f32x4*)s2;
  float Q = 0.f;
  for (int i = 0; i < 128; ++i) {
    f32x4 a = sq[i], b = wq[i];
    Q = fmaf(a[0], b[0], Q);
    Q = fmaf(a[1], b[1], Q);
    Q = fmaf(a[2], b[2], Q);
    Q = fmaf(a[3], b[3], Q);
  }
  float a = wscale[o] * sg[0];
  float ig = rsqrtf(ema[0]);
  coef[n * 512 + o] = ig * rsqrtf(a * a * Q + 1e-8f);
}

// xT[n][ic][r][c][slot s][j] = f16( x[n, ic*32 + (s^sig(r,c))*8+j, r, c] * styles * sg )
// LDS-transposed; sig = ((r*68+c+2)>>1)&3.
__global__ __launch_bounds__(256) void k_xprep(const float* __restrict__ x,
    const float* __restrict__ styles, const float* __restrict__ sg,
    _Float16* __restrict__ xT) {
  const int b = blockIdx.x;                 // 8*16*64 = 8192
  const int r = b & 63, ic = (b >> 6) & 15, n = b >> 10;
  const int tid = threadIdx.x;
  __shared__ _Float16 ls[32][64];           // 4 KB
  __shared__ float sty[32];
  if (tid < 32) sty[tid] = styles[n * 512 + ic * 32 + tid] * sg[0];
  __syncthreads();
  const float* xb = x + (((size_t)n * 512 + ic * 32) * 64 + r) * 64;
#pragma unroll
  for (int it = 0; it < 8; ++it) {
    int i = it * 4 + (tid >> 6);
    int c = tid & 63;
    float v = xb[(size_t)i * 4096 + c];     // lanes along c: 256B coalesced
    ls[i][c] = (_Float16)(v * sty[i]);
  }
  __syncthreads();
  const int c = tid >> 2, s = tid & 3;
  const int sig = ((r * 68 + c + 2) >> 1) & 3;
  const int ib = (s ^ sig) * 8;
  half8 v;
#pragma unroll
  for (int j = 0; j < 8; ++j) v[j] = ls[ib + j][c];
  *(half8*)(xT + ((((size_t)(n * 16 + ic) * 64 + r) * 64 + c) * 32) + s * 8) = v;
}

// w2[k9][ic][o][iw] = f16( cw[o, ic*32+iw, k9] * wscale[o] )
__global__ __launch_bounds__(256) void k_wprep(const float* __restrict__ cw,
    const float* __restrict__ wscale, _Float16* __restrict__ w2) {
  int t = blockIdx.x * 256 + threadIdx.x;    // 294912 slots of 8 halfs
  int s = t & 3;
  int o = (t >> 2) & 511;
  int ic = (t >> 11) & 15;
  int k9 = t >> 15;                          // 0..8
  float wsc = wscale[o];
  half8 v;
#pragma unroll
  for (int j = 0; j < 8; ++j) {
    int i = ic * 32 + s * 8 + j;
    v[j] = (_Float16)(cw[((size_t)o * 512 + i) * 9 + k9] * wsc);
  }
  *(half8*)(w2 + (size_t)t * 8) = v;
}

// Implicit-GEMM conv via MFMA f16 — R16/R17 frame (K-split x2, dbuf staging,
// 2x2 waves of 64o x 64p, acc[4][4]) + B-LDS addresses ahp[36] hoisted out of
// the ic loop (they depend only on nt,k9 — were recomputed 8x per block).
__global__ __launch_bounds__(256, 3) void k_conv(
    const _Float16* __restrict__ xT, const _Float16* __restrict__ w2,
    const float* __restrict__ coef, _Float16* __restrict__ convpart) {
  const int b = blockIdx.x;
  const int kx = b & 7;
  const int j = b >> 3;
  const int ot = kx >> 1;
  const int n = (kx & 1) * 4 + j / 70;
  const int jj0 = j % 70;
  const int pt = jj0 >> 1;
  const int kh = jj0 & 1;
  const int p0 = pt * 128;
  const int R0 = p0 / 66;
  const int oBase = ot * 128;

  const int tid = threadIdx.x;
  const int wave = tid >> 6;
  const int lane = tid & 63;
  const int wo = wave >> 1, wp = wave & 1;
  const int isub = lane >> 4;
  const int l15 = lane & 15;

  __shared__ _Float16 patch[2][10880];   // [5][68][32] halfs each, 21760 B per buf

  // precomputed B LDS half-offsets: ahp[k9*4+nt], ic-invariant
  int ahp[36];
#pragma unroll
  for (int nt = 0; nt < 4; ++nt) {
    int p = p0 + wp * 64 + nt * 16 + l15;
    if (p > 4355) p = 4355;
    int r = p / 66;
    int rl0 = r - R0;              // 0..2
    int rr20 = r - 2;
    int c0 = p - r * 66;
#pragma unroll
    for (int k9 = 0; k9 < 9; ++k9) {
      int dr = k9 / 3, dc = k9 % 3;
      int rl = rl0 + dr;
      int cl = c0 + dc;
      int sig = (((rr20 + dr) * 68 + cl) >> 1) & 3;
      ahp[k9 * 4 + nt] = (rl * 68 + cl) * 32 + ((isub ^ sig) << 3);
    }
  }
  bool valid[4];
#pragma unroll
  for (int nt = 0; nt < 4; ++nt) valid[nt] = (p0 + wp * 64 + nt * 16 + l15 < 4356);

  f32x4 acc[4][4];
#pragma unroll
  for (int mt = 0; mt < 4; ++mt)
#pragma unroll
    for (int nt = 0; nt < 4; ++nt) acc[mt][nt] = (f32x4){0.f, 0.f, 0.f, 0.f};

  const int oA = oBase + wo * 64 + l15;
  const _Float16* wp0 = w2 + (size_t)oA * 32 + isub * 8;

#pragma unroll
  for (int buf = 0; buf < 2; ++buf) {
    _Float16* dst = &patch[buf][0];
    if (tid < 80) {
      int pix = tid >> 2, s = tid & 3;
      int rl = pix >> 2, ci = pix & 3;
      int cl = (ci < 2) ? ci : (ci + 64);
      half8 z = {};
      *(half8*)(dst + (rl * 68 + cl) * 32 + s * 8) = z;
    }
#pragma unroll
    for (int rl = 0; rl < 5; ++rl) {
      int rin = R0 - 2 + rl;
      if (rin < 0 || rin >= 64) {
        for (int u = tid; u < 272; u += 256) {
          half8 z = {};
          *(half8*)(dst + rl * 68 * 32 + u * 8) = z;
        }
      }
    }
  }

  auto stage_rows = [&](int ic, int buf) {
    const _Float16* src = xT + ((size_t)(n * 16 + ic) * 4096) * 32;
    _Float16* dst = &patch[buf][0];
#pragma unroll
    for (int rl = 0; rl < 5; ++rl) {
      int rin = R0 - 2 + rl;
      if (rin >= 0 && rin < 64)
        GLL16(src + (size_t)rin * 2048 + tid * 8, dst + (rl * 68 + 2) * 32 + tid * 8);
    }
  };

  const int ic0 = kh * 8;
  stage_rows(ic0, 0);
  __syncthreads();

  for (int icl = 0; icl < 8; ++icl) {
    const int ic = ic0 + icl;
    const int buf = icl & 1;
    const _Float16* pb = &patch[buf][0];
    if (icl < 7) stage_rows(ic + 1, buf ^ 1);

#pragma unroll
    for (int k9 = 0; k9 < 9; ++k9) {
      half8 aF[4];
#pragma unroll
      for (int mt = 0; mt < 4; ++mt)
        aF[mt] = *(const half8*)(wp0 + ((size_t)(k9 * 16 + ic) * 512 + mt * 16) * 32);
#pragma unroll
      for (int nt = 0; nt < 4; ++nt) {
        half8 bF = *(const half8*)(pb + ahp[k9 * 4 + nt]);
#pragma unroll
        for (int mt = 0; mt < 4; ++mt)
          acc[mt][nt] = __builtin_amdgcn_mfma_f32_16x16x32_f16(aF[mt], bF, acc[mt][nt], 0, 0, 0);
      }
    }
    __syncthreads();
  }

  _Float16* outbase = convpart + (size_t)kh * 17842176;
#pragma unroll
  for (int mt = 0; mt < 4; ++mt) {
    const int o = oBase + wo * 64 + mt * 16 + isub * 4;
#pragma unroll
    for (int jj = 0; jj < 4; ++jj) {
      const float cf = coef[n * 512 + o + jj];
      _Float16* outp = outbase + (size_t)(n * 512 + o + jj) * 4356;
#pragma unroll
      for (int nt = 0; nt < 4; ++nt) {
        if (valid[nt]) {
          int p = p0 + wp * 64 + nt * 16 + l15;
          outp[p] = (_Float16)(acc[mt][nt][jj] * cf);
        }
      }
    }
  }
}

// Fused bias + up-FIR(x2, polyphase) + lrelu + clamp + down-FIR(/2).
// R17 verbatim (LDS-vectorized, 16-row tiles, sums 2 f16 partials).
__global__ __launch_bounds__(256) void k_flrelu(const _Float16* __restrict__ convpart,
    const float* __restrict__ cbias, const float* __restrict__ fu,
    const float* __restrict__ fd, float* __restrict__ out) {
  const int img = blockIdx.x >> 2;       // n*512+c
  const int tile = blockIdx.x & 3;
  const int P0 = tile * 16;              // output rows [P0, P0+16)
  const int c = img & 511;
  const int tid = threadIdx.x;

  __shared__ alignas(16) float As[26 * 68];  // conv rows (+bias); aliased as U chunk
  __shared__ alignas(16) float Bs[42 * 80];  // v-up rows, col offset +4, zero aprons
  __shared__ alignas(16) float Vs[42 * 64];  // after horizontal up+lrelu+down

  float fupr[12], fdr[12];
#pragma unroll
  for (int jj = 0; jj < 12; ++jj) { fupr[jj] = fu[jj]; fdr[jj] = fd[11 - jj]; }

  // stage 1: A rows [P0-4, P0+21] = partA + partB + bias; f16-pair loads
  {
    const _Float16* srcA = convpart + (size_t)img * 4356;
    const _Float16* srcB = srcA + 17842176;
    const float bias = cbias[c];
    for (int t = tid; t < 26 * 34; t += 256) {
      int r = t / 34, cp = t - r * 34;       // pair of cols (2cp, 2cp+1)
      int gr = P0 - 4 + r;
      float2 v = make_float2(0.f, 0.f);
      if (cp < 33 && gr >= 0 && gr < 66) {
        int idx = gr * 66 + 2 * cp;
        half2v a = *(const half2v*)(srcA + idx);
        half2v b2 = *(const half2v*)(srcB + idx);
        v.x = (float)a[0] + (float)b2[0] + bias;
        v.y = (float)a[1] + (float)b2[1] + bias;
      }
      *(float2*)&As[r * 68 + 2 * cp] = v;
    }
  }
  __syncthreads();

  // stage 2: vertical up-FIR, 4 cols/thread via float4 (cols m = 4g..4g+3, g<17)
  for (int t = tid; t < 42 * 17; t += 256) {
    int k = t / 17, g = t - k * 17;
    int e = k & 1, kk = (k - e) >> 1;
    const float* Ab = &As[kk * 68 + 4 * g];
    float s0 = 0.f, s1 = 0.f, s2 = 0.f, s3 = 0.f;
#pragma unroll
    for (int jj = 0; jj < 6; ++jj) {
      f32x4 a = *(const f32x4*)(Ab + (5 - jj) * 68);
      float f = e ? fupr[2 * jj + 1] : fupr[2 * jj];
      s0 = fmaf(f, a[0], s0);
      s1 = fmaf(f, a[1], s1);
      s2 = fmaf(f, a[2], s2);
      s3 = fmaf(f, a[3], s3);
    }
    f32x4 sv = {s0, s1, s2, s3};
    *(f32x4*)&Bs[k * 80 + 4 + 4 * g] = sv;    // covers B cols 0..67 (66,67 are 0)
  }
  // aprons: cols [0,4) and [72,80)
  for (int t = tid; t < 42 * 12; t += 256) {
    int k = t / 12, ci = t - k * 12;
    int col = (ci < 4) ? ci : (68 + ci);      // 0..3, 72..79
    Bs[k * 80 + col] = 0.f;
  }
  __syncthreads();        // As dead from here; reuse as U

  // stage 3 (chunked 12 rows; 12*140=1680 <= 1768 floats of As).
  // 3a: one 9-float window -> 8 U values (m = 4g..4g+3).
  float* Us = As;
  for (int kc = 0; kc < 4; ++kc) {
    const int k0 = kc * 12;
    const int nrows = imin(42 - k0, 12);
    for (int t = tid; t < nrows * 18; t += 256) {
      int kr = t / 18, g = t - kr * 18;       // g in [0,18): m base 4g <= 68
      const float* Bk = &Bs[(k0 + kr) * 80 + 4 * g];
      float b[9];
#pragma unroll
      for (int u = 0; u < 9; ++u) b[u] = Bk[u];
      float u8[8];
#pragma unroll
      for (int u = 0; u < 4; ++u) {
        float ue = 0.f, uo = 0.f;
#pragma unroll
        for (int jj = 0; jj < 6; ++jj) {
          float bb = b[u + 5 - jj];
          ue = fmaf(fupr[2 * jj], bb, ue);
          uo = fmaf(fupr[2 * jj + 1], bb, uo);
        }
        ue *= (ue >= 0.f) ? 5.65685424949238f : 1.13137084989848f;
        uo *= (uo >= 0.f) ? 5.65685424949238f : 1.13137084989848f;
        ue = fminf(256.f, fmaxf(-256.f, ue));
        uo = fminf(256.f, fmaxf(-256.f, uo));
        u8[2 * u] = ue; u8[2 * u + 1] = uo;
      }
      float* Ud = &Us[kr * 140 + 8 * g];
      f32x4 lo = {u8[0], u8[1], u8[2], u8[3]};
      *(f32x4*)(Ud) = lo;
      if (4 * g + 2 < 70) {
        f32x4 hi = {u8[4], u8[5], u8[6], u8[7]};
        *(f32x4*)(Ud + 4) = hi;
      }
    }
    __syncthreads();
    // 3b: horizontal down-FIR via 6 float2 reads
    for (int t = tid; t < nrows * 64; t += 256) {
      int kr = t >> 6, q = t & 63;
      const float* Ur = &Us[kr * 140 + 2 * q];
      float v = 0.f;
#pragma unroll
      for (int jj = 0; jj < 6; ++jj) {
        float2 u2 = *(const float2*)(Ur + 2 * jj);
        v = fmaf(fdr[2 * jj], u2.x, v);
        v = fmaf(fdr[2 * jj + 1], u2.y, v);
      }
      Vs[(k0 + kr) * 64 + q] = v;
    }
    __syncthreads();
  }

  // stage 4: vertical down-FIR, 4 outputs/thread via float4 (16 pr x 16 qg)
  {
    int pr = tid >> 4, qg = tid & 15;
    const float* Vb = &Vs[(2 * pr) * 64 + 4 * qg];
    float s0 = 0.f, s1 = 0.f, s2 = 0.f, s3 = 0.f;
#pragma unroll
    for (int jj = 0; jj < 12; ++jj) {
      f32x4 vv = *(const f32x4*)(Vb + jj * 64);
      float f = fdr[jj];
      s0 = fmaf(f, vv[0], s0);
      s1 = fmaf(f, vv[1], s1);
      s2 = fmaf(f, vv[2], s2);
      s3 = fmaf(f, vv[3], s3);
    }
    f32x4 sv = {s0, s1, s2, s3};
    *(f32x4*)(out + (size_t)img * 4096 + (P0 + pr) * 64 + 4 * qg) = sv;
  }
}

extern "C" void kernel_launch(void* const* d_in, const int* in_sizes, int n_in,
                              void* d_out, int out_size, void* d_ws, size_t ws_size,
                              hipStream_t stream) {
  const float* x   = (const float*)d_in[0];
  const float* w   = (const float*)d_in[1];
  const float* aw  = (const float*)d_in[2];
  const float* ab  = (const float*)d_in[3];
  const float* cw  = (const float*)d_in[4];
  const float* cb  = (const float*)d_in[5];
  const float* fu  = (const float*)d_in[6];
  const float* fd  = (const float*)d_in[7];
  const float* ema = (const float*)d_in[8];
  float* out = (float*)d_out;

  float* ws       = (float*)d_ws;
  float* styles   = ws;                         // 4096
  float* wsq      = styles + 4096;              // 262144
  float* wscale   = wsq + 262144;               // 512
  float* coef     = wscale + 512;               // 4096
  float* sg       = coef + 4096;                // 8
  _Float16* convpart = (_Float16*)(sg + 8);     // 2 x 17,842,176 halfs (71.4 MB)
  _Float16* xT    = convpart + 35684352;        // 16,777,216 halfs
  _Float16* w2    = xT + 16777216;              // 2,359,296 halfs
  // total = 110,725,152 B == proven footprint

  k_styles<<<16, 256, 0, stream>>>(w, aw, ab, styles);
  k_sg<<<1, 256, 0, stream>>>(styles, sg);
  k_wstats<<<512, 256, 0, stream>>>(cw, wsq, wscale);
  k_coef<<<16, 256, 0, stream>>>(styles, wsq, wscale, sg, ema, coef);
  k_xprep<<<8192, 256, 0, stream>>>(x, styles, sg, xT);
  k_wprep<<<1152, 256, 0, stream>>>(cw, wscale, w2);
  k_conv<<<2240, 256, 0, stream>>>(xT, w2, coef, convpart);
  k_flrelu<<<16384, 256, 0, stream>>>(convpart, cb, fu, fd, out);
}